// Round 3
// baseline (288.377 us; speedup 1.0000x reference)
//
#include <hip/hip_runtime.h>

// out = joints @ R + t, R = RX(roll) @ RY(pitch) @ RZ(yaw), per reference.
// Memory-bound: 169 MB in + 169 MB out (~54 us floor at 6.3 TB/s).
// Each thread handles 4 points (12 consecutive floats) via 3 aligned
// 16B loads/stores so the xyz stride-3 layout coalesces at 16 B/lane.
// Streams are non-temporal (nt): 339 MB has zero reuse, skip cache alloc.
// Native ext_vector_type used because __builtin_nontemporal_* rejects the
// HIP_vector_type struct float4.

typedef float f32x4 __attribute__((ext_vector_type(4)));

__global__ __launch_bounds__(256) void Transform_38723425141290_kernel(
    const float* __restrict__ joints,
    const float* __restrict__ orient,
    const float* __restrict__ trans,
    float* __restrict__ out,
    int n_groups,   // number of 4-point (12-float) groups
    int n_points)   // total point count
{
    // --- rotation matrix (wave-uniform scalar work, negligible) ---
    const float roll = orient[0], pitch = orient[1], yaw = orient[2];
    float sr, cr, sp, cp, sy, cy;
    sincosf(roll, &sr, &cr);
    sincosf(pitch, &sp, &cp);
    sincosf(yaw, &sy, &cy);

    const float R00 = cp * cy;
    const float R01 = -cp * sy;
    const float R02 = sp;
    const float R10 = sr * sp * cy + cr * sy;
    const float R11 = cr * cy - sr * sp * sy;
    const float R12 = -sr * cp;
    const float R20 = sr * sy - cr * sp * cy;
    const float R21 = cr * sp * sy + sr * cy;
    const float R22 = cr * cp;

    const float tx = trans[0], ty = trans[1], tz = trans[2];

    const int g = blockIdx.x * blockDim.x + threadIdx.x;

    if (g < n_groups) {
        const f32x4* jp = reinterpret_cast<const f32x4*>(joints) + (size_t)g * 3;
        f32x4 a = __builtin_nontemporal_load(jp + 0);
        f32x4 b = __builtin_nontemporal_load(jp + 1);
        f32x4 c = __builtin_nontemporal_load(jp + 2);

        // p0 = (a0,a1,a2) p1 = (a3,b0,b1) p2 = (b2,b3,c0) p3 = (c1,c2,c3)
        float ox0 = a.x * R00 + a.y * R10 + a.z * R20 + tx;
        float oy0 = a.x * R01 + a.y * R11 + a.z * R21 + ty;
        float oz0 = a.x * R02 + a.y * R12 + a.z * R22 + tz;

        float ox1 = a.w * R00 + b.x * R10 + b.y * R20 + tx;
        float oy1 = a.w * R01 + b.x * R11 + b.y * R21 + ty;
        float oz1 = a.w * R02 + b.x * R12 + b.y * R22 + tz;

        float ox2 = b.z * R00 + b.w * R10 + c.x * R20 + tx;
        float oy2 = b.z * R01 + b.w * R11 + c.x * R21 + ty;
        float oz2 = b.z * R02 + b.w * R12 + c.x * R22 + tz;

        float ox3 = c.y * R00 + c.z * R10 + c.w * R20 + tx;
        float oy3 = c.y * R01 + c.z * R11 + c.w * R21 + ty;
        float oz3 = c.y * R02 + c.z * R12 + c.w * R22 + tz;

        f32x4 o0 = {ox0, oy0, oz0, ox1};
        f32x4 o1 = {oy1, oz1, ox2, oy2};
        f32x4 o2 = {oz2, ox3, oy3, oz3};

        f32x4* op = reinterpret_cast<f32x4*>(out) + (size_t)g * 3;
        __builtin_nontemporal_store(o0, op + 0);
        __builtin_nontemporal_store(o1, op + 1);
        __builtin_nontemporal_store(o2, op + 2);
    }

    // scalar tail (n_points % 4 != 0) — dead for this shape, kept for safety
    const int tail_base = n_groups * 4;
    const int tail_idx = tail_base + g;
    if (g < (n_points - tail_base)) {
        const float x = joints[(size_t)tail_idx * 3 + 0];
        const float y = joints[(size_t)tail_idx * 3 + 1];
        const float z = joints[(size_t)tail_idx * 3 + 2];
        out[(size_t)tail_idx * 3 + 0] = x * R00 + y * R10 + z * R20 + tx;
        out[(size_t)tail_idx * 3 + 1] = x * R01 + y * R11 + z * R21 + ty;
        out[(size_t)tail_idx * 3 + 2] = x * R02 + y * R12 + z * R22 + tz;
    }
}

extern "C" void kernel_launch(void* const* d_in, const int* in_sizes, int n_in,
                              void* d_out, int out_size, void* d_ws, size_t ws_size,
                              hipStream_t stream) {
    const float* joints = (const float*)d_in[0];
    const float* orient = (const float*)d_in[1];
    const float* trans  = (const float*)d_in[2];
    float* out = (float*)d_out;

    const int n_floats = in_sizes[0];
    const int n_points = n_floats / 3;
    const int n_groups = n_points / 4;

    const int block = 256;
    int work = n_groups > 0 ? n_groups : 1;
    const int grid = (work + block - 1) / block;

    Transform_38723425141290_kernel<<<dim3(grid), dim3(block), 0, stream>>>(
        joints, orient, trans, out, n_groups, n_points);
}